// Round 15
// baseline (408.984 us; speedup 1.0000x reference)
//
#include <hip/hip_runtime.h>

// LSTM forward, T=2048, B=1024, I=15, H=10 (PyTorch gate order i,f,g,o).
// Producer/consumer wave specialization, one 128-thread block per batch row:
//   wave 0 (consumer, prio 1): serial recurrence, ~15-level chain, ~38 ops/step
//   wave 1 (producer, prio 0): x.Wih projection via v_mfma_f32_32x32x16_f16
//                              (2 MFMAs / 32-step block) + h global stores
// R14 lesson: chain levels now dominate (marginal op cost ~1.5cy, level ~12cy).
// R15 level cuts:
//   - f32 tail: readlane h directly (1 level) vs dpp+cvt+rl (3 levels); dot via
//     five 2-deep f32 FMA chains + add3/add.
//   - gate combine reorder: iv/fv/ov = dpp(rc) directly (sigmoid act == rc);
//     g2 = fma(-4log2e, rc, 2log2e) in parallel (only the p=2 source lane
//     matters, constants uniform); cs = fma(gv, iv, fv*cs) with fv*cs off the
//     g2 path. Saves 1 mid-chain level vs act-fma -> dpp -> mul -> fma.
//   - hsh rows padded to 65 floats: kills the 8-way bank conflict in HSTORE
//     reads (5.6M conflict cycles on the shared LDS pipe).
// MFMA layouts (verified, learn_hip m74/m101): D: col=lane&31,
// row=(reg&3)+8*(reg>>2)+4*(lane>>5); A: row=lane&31, k=8*(lane>>5)+e; B same.
// Weight prescale: sigmoid rows -log2e, tanh rows +2log2e; g-row activation
// 2log2e*tanh so cell state is carried as cs = 2log2e*c and feeds exp2
// directly. h = ov*tanh(c) = fma(-2ov, rcp(1+2^cs), ov).

#define T_N  2048
#define B_N  1024
#define I_N  15
#define H_N  10
#define DQ   32            // steps per block (= MFMA M dimension)
#define NBLK (T_N / DQ)    // 64 blocks
#define LPAD 64
#define HPAD 65            // hsh row pad: bank = (dd+4j)%32 -> <=2-way (free)

typedef _Float16 f16x8   __attribute__((ext_vector_type(8)));
typedef float    f32x16  __attribute__((ext_vector_type(16)));

template <int CTRL>
static __device__ __forceinline__ float dppf(float v) {
    return __builtin_bit_cast(float,
        __builtin_amdgcn_mov_dpp(__builtin_bit_cast(int, v), CTRL, 0xF, 0xF, true));
}
static __device__ __forceinline__ float rl(float v, int lane) {
    return __builtin_bit_cast(float, __builtin_amdgcn_readlane(__builtin_bit_cast(int, v), lane));
}

// light barrier: LDS-consistent, does NOT drain vmcnt
#define BAR() asm volatile("s_waitcnt lgkmcnt(0)\n\ts_barrier" ::: "memory")

// ---- consumer: one LSTM step, ~15-level serial cycle, pure ALU ----
// Cycle: rl -> fma x2 -> add3 -> add -> exp2 -> add -> rcp -> dpp ->
//        (g2 | fv*cs) -> fma cs -> exp2 -> add -> rcp -> fma h -> rl.
#define CSTEP(xav) do {                                                           \
    float d0 = fmaf(hs0, wh0, (xav)); d0 = fmaf(hs5, wh5, d0);                    \
    float d1 = hs1 * wh1;             d1 = fmaf(hs6, wh6, d1);                    \
    float d2 = hs2 * wh2;             d2 = fmaf(hs7, wh7, d2);                    \
    float d3 = hs3 * wh3;             d3 = fmaf(hs8, wh8, d3);                    \
    float d4 = hs4 * wh4;             d4 = fmaf(hs9, wh9, d4);                    \
    const float acc = (d0 + d1 + d2) + (d3 + d4);                                 \
    const float e   = __builtin_amdgcn_exp2f(acc);                                \
    const float rc  = __builtin_amdgcn_rcpf(1.0f + e);                            \
    const float iv  = dppf<0x00>(rc);    /* sigmoid: act == rc */                 \
    const float fv  = dppf<0x55>(rc);                                             \
    const float ov  = dppf<0xFF>(rc);                                             \
    const float g2  = fmaf(-5.7707801635558534f, rc, 2.8853900817779267f);        \
    const float gv  = dppf<0xAA>(g2);    /* 2log2e*tanh, from p=2 lane */         \
    const float fvcs = fv * cs;                                                   \
    cs = fmaf(gv, iv, fvcs);             /* cs = 2log2e * c */                    \
    const float tt = __builtin_amdgcn_exp2f(cs);                                  \
    const float rr = __builtin_amdgcn_rcpf(1.0f + tt);                            \
    const float ovm2 = -2.0f * ov;       /* off-chain */                          \
    h = fmaf(ovm2, rr, ov);                                                       \
    hs0 = rl(h, 0);  hs1 = rl(h, 4);  hs2 = rl(h, 8);  hs3 = rl(h, 12);           \
    hs4 = rl(h, 16); hs5 = rl(h, 20); hs6 = rl(h, 24); hs7 = rl(h, 28);           \
    hs8 = rl(h, 32); hs9 = rl(h, 36);                                             \
} while (0)

// ---- consumer: one block: DQ steps on XC; prefetch next block into XN
//      (one ds_read per step, slot SLOTN); h -> hsh[PAR] (one ds_write/step) ----
#define CBLOCK(XC, XN, SLOTN, PAR) do {                                           \
    const float* nb = &buf[SLOTN][0][crow];                                       \
    _Pragma("unroll")                                                             \
    for (int d = 0; d < DQ; ++d) {                                                \
        CSTEP(XC[d]);                                                             \
        XN[d] = nb[d * LPAD];                                                     \
        hsh[PAR][d][lane] = h;                                                    \
    }                                                                             \
} while (0)

// ---- producer: load x for block KB into xr (k<15; pad 0; clamped t) ----
#define PLOADX(KB) do {                                                           \
    int t = (KB) * DQ + trow; if (t > T_N - 1) t = T_N - 1;                       \
    const float* xp = x + ((size_t)t * B_N + b) * I_N + koff;                     \
    _Pragma("unroll")                                                             \
    for (int e = 0; e < 8; ++e) xr[e] = (koff + e < I_N) ? xp[e] : 0.0f;          \
} while (0)

// ---- producer: 2 MFMAs project xr's block into buf[SLOT] ----
#define PPROJ(SLOT) do {                                                          \
    f16x8 af;                                                                     \
    _Pragma("unroll")                                                             \
    for (int e = 0; e < 8; ++e) af[e] = (_Float16)xr[e];                          \
    const f32x16 dA = __builtin_amdgcn_mfma_f32_32x32x16_f16(af, bf0, z16, 0, 0, 0); \
    const f32x16 dB = __builtin_amdgcn_mfma_f32_32x32x16_f16(af, bf1, z16, 0, 0, 0); \
    _Pragma("unroll")                                                             \
    for (int r = 0; r < 16; ++r) {                                                \
        const int rw = (r & 3) + 8 * (r >> 2) + rbase;                            \
        buf[SLOT][rw][ncol]      = dA[r];                                         \
        buf[SLOT][rw][ncol + 32] = dB[r];   /* cols 40..63 land in pad */         \
    }                                                                             \
} while (0)

// ---- producer: store h block MB from LDS ring to global ----
#define HSTORE(MB) do {                                                           \
    const int par_ = (MB) & 1;                                                    \
    if (sact) {                                                                   \
        _Pragma("unroll")                                                         \
        for (int r = 0; r < 6; ++r) {                                             \
            const int dd = r * 6 + sl_d;                                          \
            if (dd < DQ)                                                          \
                out[((size_t)(MB) * DQ + dd) * (B_N * H_N) + b * H_N + sl_j]      \
                    = hsh[par_][dd][4 * sl_j];                                    \
        }                                                                         \
    }                                                                             \
} while (0)

__global__ __launch_bounds__(128, 2)
void lstm_pc(const float* __restrict__ x, const float* __restrict__ h0,
             const float* __restrict__ c0, const float* __restrict__ Wih,
             const float* __restrict__ Whh, float* __restrict__ out)
{
    __shared__ float buf[3][DQ][LPAD];   // 24 KB pre-activations (triple-buffered)
    __shared__ float hsh[2][DQ][HPAD];   // 16.6 KB h ring (padded, conflict-free)

    const int tid  = threadIdx.x;
    const int wave = tid >> 6;           // 0 = consumer, 1 = producer
    const int lane = tid & 63;
    const int b    = blockIdx.x;
    const float LOG2E = 1.4426950408889634f;

    // ---- producer state ----
    const int trow  = lane & 31;         // timestep within block (A row)
    const int koff  = (lane >> 5) * 8;   // k slice
    const int ncol  = lane & 31;         // gate column (D col)
    const int rbase = 4 * (lane >> 5);   // D row offset
    const int sl_j  = lane % H_N;        // h-store mapping
    const int sl_d  = lane / H_N;
    const bool sact = lane < 60;
    f16x8 bf0, bf1;
    f32x16 z16;
    float xr[8];

    // ---- consumer state ----
    const int p = lane & 3;
    int j = lane >> 2; if (j > H_N - 1) j = H_N - 1;
    const int crow = p * H_N + j;
    const bool writer = (wave == 0) && (p == 0) && (lane < 4 * H_N);
    float wh0, wh1, wh2, wh3, wh4, wh5, wh6, wh7, wh8, wh9;
    float cs, h;
    float hs0, hs1, hs2, hs3, hs4, hs5, hs6, hs7, hs8, hs9;
    float xqA[DQ], xqB[DQ];

    if (wave == 1) {
        __builtin_amdgcn_s_setprio(0);
        // B fragments (constant): B[k][n] = sg(n)*Wih[n][k]; k>=15 or n>=40 -> 0
#pragma unroll
        for (int e = 0; e < 8; ++e) {
            const int k = koff + e;
            {
                const int n = ncol;
                const float sgn = (n >= 20 && n < 30) ? 2.0f * LOG2E : -LOG2E;
                bf0[e] = (_Float16)((k < I_N) ? sgn * Wih[n * I_N + k] : 0.0f);
            }
            {
                const int n = 32 + ncol;
                const float sgn = (n >= 20 && n < 30) ? 2.0f * LOG2E : -LOG2E;
                bf1[e] = (_Float16)((k < I_N && n < 40) ? sgn * Wih[n * I_N + k] : 0.0f);
            }
        }
#pragma unroll
        for (int r = 0; r < 16; ++r) z16[r] = 0.0f;
        // prologue: proj(0)->slot0, proj(1)->slot1; stage x(block 2)
        PLOADX(0);
        PPROJ(0);
        PLOADX(1);
        PPROJ(1);
        PLOADX(2);
    } else {
        __builtin_amdgcn_s_setprio(1);
        // prescaled Whh row for gate row crow (f32)
        const float sg = (p == 2) ? 2.0f * LOG2E : -LOG2E;
        const float* wr = Whh + crow * H_N;
        wh0 = sg * wr[0]; wh1 = sg * wr[1]; wh2 = sg * wr[2]; wh3 = sg * wr[3];
        wh4 = sg * wr[4]; wh5 = sg * wr[5]; wh6 = sg * wr[6]; wh7 = sg * wr[7];
        wh8 = sg * wr[8]; wh9 = sg * wr[9];
        cs = c0[b * H_N + j] * (2.0f * LOG2E);
        h  = h0[b * H_N + j];
        hs0 = rl(h, 0);  hs1 = rl(h, 4);  hs2 = rl(h, 8);  hs3 = rl(h, 12);
        hs4 = rl(h, 16); hs5 = rl(h, 20); hs6 = rl(h, 24); hs7 = rl(h, 28);
        hs8 = rl(h, 32); hs9 = rl(h, 36);
    }
    BAR();   // slot0/slot1 projections visible

    // consumer: one-time burst read of block 0 (the only block-top stall)
    if (wave == 0) {
#pragma unroll
        for (int d = 0; d < DQ; ++d) xqA[d] = buf[0][d][crow];
    }

    // Slot rotation invariant at iter i: consumer consumes regs (block i),
    // prefetches block i+1 from slot slR; producer projects block i+2 into slW.
    int slR = 1, slW = 2, slO = 0;
    for (int m = 0; m < NBLK; m += 2) {
        if (wave == 1) {
            PPROJ(slW);
            PLOADX(m + 3);
            if (m > 0) HSTORE(m - 1);
        } else {
            CBLOCK(xqA, xqB, slR, 0);
        }
        BAR();
        { const int t = slO; slO = slR; slR = slW; slW = t; }
        if (wave == 1) {
            PPROJ(slW);
            PLOADX(m + 4);
            HSTORE(m);
        } else {
            CBLOCK(xqB, xqA, slR, 1);
        }
        BAR();
        { const int t = slO; slO = slR; slR = slW; slW = t; }
    }

    // epilogue: last h block from producer; hN/cN from consumer
    if (wave == 1) {
        HSTORE(NBLK - 1);
    } else if (writer) {
        const size_t base = (size_t)T_N * B_N * H_N;
        out[base + b * H_N + j] = h;                                          // hN
        out[base + (size_t)B_N * H_N + b * H_N + j] = cs * 0.34657359027997264f; // cN
    }
}

extern "C" void kernel_launch(void* const* d_in, const int* in_sizes, int n_in,
                              void* d_out, int out_size, void* d_ws, size_t ws_size,
                              hipStream_t stream) {
    const float* x   = (const float*)d_in[0];
    const float* h0  = (const float*)d_in[1];
    const float* c0  = (const float*)d_in[2];
    const float* Wih = (const float*)d_in[3];
    const float* Whh = (const float*)d_in[4];
    float* out = (float*)d_out;
    lstm_pc<<<dim3(B_N), dim3(128), 0, stream>>>(x, h0, c0, Wih, Whh, out);
}

// Round 16
// 186.936 us; speedup vs baseline: 2.1878x; 2.1878x over previous
//
#include <hip/hip_runtime.h>

// LSTM forward, T=2048, B=1024, I=15, H=10 (PyTorch gate order i,f,g,o).
// Producer/consumer wave specialization, one 128-thread block per batch row:
//   wave 0 (consumer, prio 1): serial recurrence, ~15-level chain
//   wave 1 (producer, prio 0): x.Wih projection via v_mfma_f32_32x32x16_f16
//                              (2 MFMAs / 32-step block) + h global stores
// R15 lesson (occupancy cliff): LDS must stay <= 40960 B so FOUR 2-wave blocks
// fit per CU (1024 blocks on 256 CUs need 4/CU; 41472 B -> 3/CU -> multi-pass
// grid, 2.4x wall). So: hsh is UNPADDED [2][32][64] and bank conflicts are
// fixed with an XOR skew instead of a pad:
//   store: hsh[par][d][lane ^ d]; read: hsh[par][dd][(4*sl_j) ^ dd]
//   (bijective per d -> no collisions; write banks 2-way (free); read <=3-way
//    vs 6-8-way before).
// Chain (R15's 15-level CSTEP, kept): iv/fv/ov = dpp(rc) directly; g2 =
// fma(-4log2e, rc, 2log2e) in parallel; cs = fma(gv, iv, fv*cs); f32 readlane
// h tail. Weight prescale: sigmoid rows -log2e, tanh rows +2log2e; cell state
// carried as cs = 2log2e*c. h = ov*tanh(c) = fma(-2ov, rcp(1+2^cs), ov).
// MFMA layouts (verified, learn_hip m74/m101): D: col=lane&31,
// row=(reg&3)+8*(reg>>2)+4*(lane>>5); A: row=lane&31, k=8*(lane>>5)+e; B same.

#define T_N  2048
#define B_N  1024
#define I_N  15
#define H_N  10
#define DQ   32            // steps per block (= MFMA M dimension)
#define NBLK (T_N / DQ)    // 64 blocks
#define LPAD 64

typedef _Float16 f16x8   __attribute__((ext_vector_type(8)));
typedef float    f32x16  __attribute__((ext_vector_type(16)));

template <int CTRL>
static __device__ __forceinline__ float dppf(float v) {
    return __builtin_bit_cast(float,
        __builtin_amdgcn_mov_dpp(__builtin_bit_cast(int, v), CTRL, 0xF, 0xF, true));
}
static __device__ __forceinline__ float rl(float v, int lane) {
    return __builtin_bit_cast(float, __builtin_amdgcn_readlane(__builtin_bit_cast(int, v), lane));
}

// light barrier: LDS-consistent, does NOT drain vmcnt
#define BAR() asm volatile("s_waitcnt lgkmcnt(0)\n\ts_barrier" ::: "memory")

// ---- consumer: one LSTM step, ~15-level serial cycle, pure ALU ----
// Cycle: rl -> fma x2 -> add3 -> add -> exp2 -> add -> rcp -> dpp ->
//        (g2 | fv*cs) -> fma cs -> exp2 -> add -> rcp -> fma h -> rl.
#define CSTEP(xav) do {                                                           \
    float d0 = fmaf(hs0, wh0, (xav)); d0 = fmaf(hs5, wh5, d0);                    \
    float d1 = hs1 * wh1;             d1 = fmaf(hs6, wh6, d1);                    \
    float d2 = hs2 * wh2;             d2 = fmaf(hs7, wh7, d2);                    \
    float d3 = hs3 * wh3;             d3 = fmaf(hs8, wh8, d3);                    \
    float d4 = hs4 * wh4;             d4 = fmaf(hs9, wh9, d4);                    \
    const float acc = (d0 + d1 + d2) + (d3 + d4);                                 \
    const float e   = __builtin_amdgcn_exp2f(acc);                                \
    const float rc  = __builtin_amdgcn_rcpf(1.0f + e);                            \
    const float iv  = dppf<0x00>(rc);    /* sigmoid: act == rc */                 \
    const float fv  = dppf<0x55>(rc);                                             \
    const float ov  = dppf<0xFF>(rc);                                             \
    const float g2  = fmaf(-5.7707801635558534f, rc, 2.8853900817779267f);        \
    const float gv  = dppf<0xAA>(g2);    /* 2log2e*tanh, from p=2 lane */         \
    const float fvcs = fv * cs;                                                   \
    cs = fmaf(gv, iv, fvcs);             /* cs = 2log2e * c */                    \
    const float tt = __builtin_amdgcn_exp2f(cs);                                  \
    const float rr = __builtin_amdgcn_rcpf(1.0f + tt);                            \
    const float ovm2 = -2.0f * ov;       /* off-chain */                          \
    h = fmaf(ovm2, rr, ov);                                                       \
    hs0 = rl(h, 0);  hs1 = rl(h, 4);  hs2 = rl(h, 8);  hs3 = rl(h, 12);           \
    hs4 = rl(h, 16); hs5 = rl(h, 20); hs6 = rl(h, 24); hs7 = rl(h, 28);           \
    hs8 = rl(h, 32); hs9 = rl(h, 36);                                             \
} while (0)

// ---- consumer: one block: DQ steps on XC; prefetch next block into XN
//      (one ds_read per step, slot SLOTN); h -> hsh[PAR] (XOR-skewed col) ----
#define CBLOCK(XC, XN, SLOTN, PAR) do {                                           \
    const float* nb = &buf[SLOTN][0][crow];                                       \
    _Pragma("unroll")                                                             \
    for (int d = 0; d < DQ; ++d) {                                                \
        CSTEP(XC[d]);                                                             \
        XN[d] = nb[d * LPAD];                                                     \
        hsh[PAR][d][lane ^ d] = h;                                                \
    }                                                                             \
} while (0)

// ---- producer: load x for block KB into xr (k<15; pad 0; clamped t) ----
#define PLOADX(KB) do {                                                           \
    int t = (KB) * DQ + trow; if (t > T_N - 1) t = T_N - 1;                       \
    const float* xp = x + ((size_t)t * B_N + b) * I_N + koff;                     \
    _Pragma("unroll")                                                             \
    for (int e = 0; e < 8; ++e) xr[e] = (koff + e < I_N) ? xp[e] : 0.0f;          \
} while (0)

// ---- producer: 2 MFMAs project xr's block into buf[SLOT] ----
#define PPROJ(SLOT) do {                                                          \
    f16x8 af;                                                                     \
    _Pragma("unroll")                                                             \
    for (int e = 0; e < 8; ++e) af[e] = (_Float16)xr[e];                          \
    const f32x16 dA = __builtin_amdgcn_mfma_f32_32x32x16_f16(af, bf0, z16, 0, 0, 0); \
    const f32x16 dB = __builtin_amdgcn_mfma_f32_32x32x16_f16(af, bf1, z16, 0, 0, 0); \
    _Pragma("unroll")                                                             \
    for (int r = 0; r < 16; ++r) {                                                \
        const int rw = (r & 3) + 8 * (r >> 2) + rbase;                            \
        buf[SLOT][rw][ncol]      = dA[r];                                         \
        buf[SLOT][rw][ncol + 32] = dB[r];   /* cols 40..63 land in pad */         \
    }                                                                             \
} while (0)

// ---- producer: store h block MB from LDS ring to global (skewed read) ----
#define HSTORE(MB) do {                                                           \
    const int par_ = (MB) & 1;                                                    \
    if (sact) {                                                                   \
        _Pragma("unroll")                                                         \
        for (int r = 0; r < 6; ++r) {                                             \
            const int dd = r * 6 + sl_d;                                          \
            if (dd < DQ)                                                          \
                out[((size_t)(MB) * DQ + dd) * (B_N * H_N) + b * H_N + sl_j]      \
                    = hsh[par_][dd][(4 * sl_j) ^ dd];                             \
        }                                                                         \
    }                                                                             \
} while (0)

__global__ __launch_bounds__(128, 2)
void lstm_pc(const float* __restrict__ x, const float* __restrict__ h0,
             const float* __restrict__ c0, const float* __restrict__ Wih,
             const float* __restrict__ Whh, float* __restrict__ out)
{
    __shared__ float buf[3][DQ][LPAD];   // 24576 B pre-activations (triple-buf)
    __shared__ float hsh[2][DQ][64];     // 16384 B h ring -> total 40960 B
                                         // == 160KiB/4: four blocks/CU fit

    const int tid  = threadIdx.x;
    const int wave = tid >> 6;           // 0 = consumer, 1 = producer
    const int lane = tid & 63;
    const int b    = blockIdx.x;
    const float LOG2E = 1.4426950408889634f;

    // ---- producer state ----
    const int trow  = lane & 31;         // timestep within block (A row)
    const int koff  = (lane >> 5) * 8;   // k slice
    const int ncol  = lane & 31;         // gate column (D col)
    const int rbase = 4 * (lane >> 5);   // D row offset
    const int sl_j  = lane % H_N;        // h-store mapping
    const int sl_d  = lane / H_N;
    const bool sact = lane < 60;
    f16x8 bf0, bf1;
    f32x16 z16;
    float xr[8];

    // ---- consumer state ----
    const int p = lane & 3;
    int j = lane >> 2; if (j > H_N - 1) j = H_N - 1;
    const int crow = p * H_N + j;
    const bool writer = (wave == 0) && (p == 0) && (lane < 4 * H_N);
    float wh0, wh1, wh2, wh3, wh4, wh5, wh6, wh7, wh8, wh9;
    float cs, h;
    float hs0, hs1, hs2, hs3, hs4, hs5, hs6, hs7, hs8, hs9;
    float xqA[DQ], xqB[DQ];

    if (wave == 1) {
        __builtin_amdgcn_s_setprio(0);
        // B fragments (constant): B[k][n] = sg(n)*Wih[n][k]; k>=15 or n>=40 -> 0
#pragma unroll
        for (int e = 0; e < 8; ++e) {
            const int k = koff + e;
            {
                const int n = ncol;
                const float sgn = (n >= 20 && n < 30) ? 2.0f * LOG2E : -LOG2E;
                bf0[e] = (_Float16)((k < I_N) ? sgn * Wih[n * I_N + k] : 0.0f);
            }
            {
                const int n = 32 + ncol;
                const float sgn = (n >= 20 && n < 30) ? 2.0f * LOG2E : -LOG2E;
                bf1[e] = (_Float16)((k < I_N && n < 40) ? sgn * Wih[n * I_N + k] : 0.0f);
            }
        }
#pragma unroll
        for (int r = 0; r < 16; ++r) z16[r] = 0.0f;
        // prologue: proj(0)->slot0, proj(1)->slot1; stage x(block 2)
        PLOADX(0);
        PPROJ(0);
        PLOADX(1);
        PPROJ(1);
        PLOADX(2);
    } else {
        __builtin_amdgcn_s_setprio(1);
        // prescaled Whh row for gate row crow (f32)
        const float sg = (p == 2) ? 2.0f * LOG2E : -LOG2E;
        const float* wr = Whh + crow * H_N;
        wh0 = sg * wr[0]; wh1 = sg * wr[1]; wh2 = sg * wr[2]; wh3 = sg * wr[3];
        wh4 = sg * wr[4]; wh5 = sg * wr[5]; wh6 = sg * wr[6]; wh7 = sg * wr[7];
        wh8 = sg * wr[8]; wh9 = sg * wr[9];
        cs = c0[b * H_N + j] * (2.0f * LOG2E);
        h  = h0[b * H_N + j];
        hs0 = rl(h, 0);  hs1 = rl(h, 4);  hs2 = rl(h, 8);  hs3 = rl(h, 12);
        hs4 = rl(h, 16); hs5 = rl(h, 20); hs6 = rl(h, 24); hs7 = rl(h, 28);
        hs8 = rl(h, 32); hs9 = rl(h, 36);
    }
    BAR();   // slot0/slot1 projections visible

    // consumer: one-time burst read of block 0 (the only block-top stall)
    if (wave == 0) {
#pragma unroll
        for (int d = 0; d < DQ; ++d) xqA[d] = buf[0][d][crow];
    }

    // Slot rotation invariant at iter i: consumer consumes regs (block i),
    // prefetches block i+1 from slot slR; producer projects block i+2 into slW.
    int slR = 1, slW = 2, slO = 0;
    for (int m = 0; m < NBLK; m += 2) {
        if (wave == 1) {
            PPROJ(slW);
            PLOADX(m + 3);
            if (m > 0) HSTORE(m - 1);
        } else {
            CBLOCK(xqA, xqB, slR, 0);
        }
        BAR();
        { const int t = slO; slO = slR; slR = slW; slW = t; }
        if (wave == 1) {
            PPROJ(slW);
            PLOADX(m + 4);
            HSTORE(m);
        } else {
            CBLOCK(xqB, xqA, slR, 1);
        }
        BAR();
        { const int t = slO; slO = slR; slR = slW; slW = t; }
    }

    // epilogue: last h block from producer; hN/cN from consumer
    if (wave == 1) {
        HSTORE(NBLK - 1);
    } else if (writer) {
        const size_t base = (size_t)T_N * B_N * H_N;
        out[base + b * H_N + j] = h;                                          // hN
        out[base + (size_t)B_N * H_N + b * H_N + j] = cs * 0.34657359027997264f; // cN
    }
}

extern "C" void kernel_launch(void* const* d_in, const int* in_sizes, int n_in,
                              void* d_out, int out_size, void* d_ws, size_t ws_size,
                              hipStream_t stream) {
    const float* x   = (const float*)d_in[0];
    const float* h0  = (const float*)d_in[1];
    const float* c0  = (const float*)d_in[2];
    const float* Wih = (const float*)d_in[3];
    const float* Whh = (const float*)d_in[4];
    float* out = (float*)d_out;
    lstm_pc<<<dim3(B_N), dim3(128), 0, stream>>>(x, h0, c0, Wih, Whh, out);
}

// Round 17
// 178.187 us; speedup vs baseline: 2.2953x; 1.0491x over previous
//
#include <hip/hip_runtime.h>

// LSTM forward, T=2048, B=1024, I=15, H=10 (PyTorch gate order i,f,g,o).
// Producer/consumer wave specialization, one 128-thread block per batch row:
//   wave 0 (consumer, prio 1): serial recurrence (f16 fdot2 dot, ~26 ops/step)
//   wave 1 (producer, prio 0): x.Wih projection via v_mfma_f32_32x32x16_f16
//                              (2 MFMAs / 32-step block) + h global stores
// R13/R14/R16 fit: step ~= 1cy*levels + 1cy*ops + ~185cy CONSTANT — the
// constant is the 4 quarter-rate transcendentals (2x exp2 + 2x rcp, wave64
// ~16 issue-cy each + latency), which are the LSTM's algorithmic serial floor.
// This round composites the best-measured pieces:
//   - R14 f16 CSTEP (best step: 231cy; 5 fdot2 + packed h broadcast)
//   - g2 gate-combine reorder (iv/fv/ov = dpp(rc) directly; gv = dpp(g2),
//     g2 = fma(-4log2e, rc, 2log2e); cs = fma(gv, iv, fv*cs)) — saves the
//     act-fma level
//   - R16 XOR-skewed hsh (producer HSTORE bank conflicts 5.6M -> 2.8M, 0 LDS)
//   - LDS pinned at 40960 B = 160KiB/4 (occupancy: 4 blocks/CU — R15's cliff)
// MFMA layouts (verified, learn_hip m74/m101): D: col=lane&31,
// row=(reg&3)+8*(reg>>2)+4*(lane>>5); A: row=lane&31, k=8*(lane>>5)+e; B same.
// Weight prescale: sigmoid rows -log2e, tanh rows +2log2e; cell state carried
// as cs = 2log2e*c (feeds exp2 directly). h = ov*tanh(c) = fma(-2ov, rr, ov).

#define T_N  2048
#define B_N  1024
#define I_N  15
#define H_N  10
#define DQ   32            // steps per block (= MFMA M dimension)
#define NBLK (T_N / DQ)    // 64 blocks
#define LPAD 64

typedef _Float16 half2_t __attribute__((ext_vector_type(2)));
typedef _Float16 f16x8   __attribute__((ext_vector_type(8)));
typedef float    f32x16  __attribute__((ext_vector_type(16)));

template <int CTRL>
static __device__ __forceinline__ float dppf(float v) {
    return __builtin_bit_cast(float,
        __builtin_amdgcn_mov_dpp(__builtin_bit_cast(int, v), CTRL, 0xF, 0xF, true));
}
static __device__ __forceinline__ float rl(float v, int lane) {
    return __builtin_bit_cast(float, __builtin_amdgcn_readlane(__builtin_bit_cast(int, v), lane));
}
static __device__ __forceinline__ unsigned rlu(unsigned v, int lane) {
    return (unsigned)__builtin_amdgcn_readlane((int)v, lane);
}
static __device__ __forceinline__ half2_t h2(unsigned u) {
    return __builtin_bit_cast(half2_t, u);
}

// light barrier: LDS-consistent, does NOT drain vmcnt
#define BAR() asm volatile("s_waitcnt lgkmcnt(0)\n\ts_barrier" ::: "memory")

// ---- consumer: one LSTM step; f16 packed h + fdot2 dot + g2 reorder ----
// Cycle: rl -> fdot2 x2 -> add x2 -> exp2 -> add -> rcp -> dpp ->
//        (g2|fv*cs) -> fma cs -> exp2 -> add -> rcp -> fma h -> dpp -> cvt -> rl
#define CSTEP(xav) do {                                                           \
    float A  = __builtin_amdgcn_fdot2(h2(hp0), wf0, (xav), false);                \
    A        = __builtin_amdgcn_fdot2(h2(hp1), wf1, A,     false);                \
    float Bv = __builtin_amdgcn_fdot2(h2(hp2), wf2, 0.f,   false);                \
    Bv       = __builtin_amdgcn_fdot2(h2(hp3), wf3, Bv,    false);                \
    const float Cv = __builtin_amdgcn_fdot2(h2(hp4), wf4, 0.f, false);            \
    const float acc = (A + Bv) + Cv;                                              \
    const float e   = __builtin_amdgcn_exp2f(acc);                                \
    const float rc  = __builtin_amdgcn_rcpf(1.0f + e);                            \
    const float iv  = dppf<0x00>(rc);    /* sigmoid: act == rc */                 \
    const float fv  = dppf<0x55>(rc);                                             \
    const float ov  = dppf<0xFF>(rc);                                             \
    const float g2  = fmaf(-5.7707801635558534f, rc, 2.8853900817779267f);        \
    const float gv  = dppf<0xAA>(g2);    /* 2log2e*tanh, from p=2 lane */         \
    const float fvcs = fv * cs;                                                   \
    cs = fmaf(gv, iv, fvcs);             /* cs = 2log2e * c */                    \
    const float tt = __builtin_amdgcn_exp2f(cs);                                  \
    const float rr = __builtin_amdgcn_rcpf(1.0f + tt);                            \
    const float ovm2 = -2.0f * ov;       /* off-chain */                          \
    h = fmaf(ovm2, rr, ov);                                                       \
    const float hbv = dppf<0x104>(h);    /* row_shl:4 -> lane i reads i+4 */      \
    const unsigned pkh = __builtin_bit_cast(unsigned,                             \
                             __builtin_amdgcn_cvt_pkrtz(h, hbv));                 \
    hp0 = rlu(pkh, 0); hp1 = rlu(pkh, 8); hp2 = rlu(pkh, 16);                     \
    hp3 = rlu(pkh, 24); hp4 = rlu(pkh, 32);                                       \
} while (0)

// ---- consumer: one block: DQ steps on XC; prefetch next block into XN
//      (one ds_read per step, slot SLOTN); h -> hsh[PAR] (XOR-skewed col) ----
#define CBLOCK(XC, XN, SLOTN, PAR) do {                                           \
    const float* nb = &buf[SLOTN][0][crow];                                       \
    _Pragma("unroll")                                                             \
    for (int d = 0; d < DQ; ++d) {                                                \
        CSTEP(XC[d]);                                                             \
        XN[d] = nb[d * LPAD];                                                     \
        hsh[PAR][d][lane ^ d] = h;                                                \
    }                                                                             \
} while (0)

// ---- producer: load x for block KB into xr (k<15; pad 0; clamped t) ----
#define PLOADX(KB) do {                                                           \
    int t = (KB) * DQ + trow; if (t > T_N - 1) t = T_N - 1;                       \
    const float* xp = x + ((size_t)t * B_N + b) * I_N + koff;                     \
    _Pragma("unroll")                                                             \
    for (int e = 0; e < 8; ++e) xr[e] = (koff + e < I_N) ? xp[e] : 0.0f;          \
} while (0)

// ---- producer: 2 MFMAs project xr's block into buf[SLOT] ----
#define PPROJ(SLOT) do {                                                          \
    f16x8 af;                                                                     \
    _Pragma("unroll")                                                             \
    for (int e = 0; e < 8; ++e) af[e] = (_Float16)xr[e];                          \
    const f32x16 dA = __builtin_amdgcn_mfma_f32_32x32x16_f16(af, bf0, z16, 0, 0, 0); \
    const f32x16 dB = __builtin_amdgcn_mfma_f32_32x32x16_f16(af, bf1, z16, 0, 0, 0); \
    _Pragma("unroll")                                                             \
    for (int r = 0; r < 16; ++r) {                                                \
        const int rw = (r & 3) + 8 * (r >> 2) + rbase;                            \
        buf[SLOT][rw][ncol]      = dA[r];                                         \
        buf[SLOT][rw][ncol + 32] = dB[r];   /* cols 40..63 land in pad */         \
    }                                                                             \
} while (0)

// ---- producer: store h block MB from LDS ring to global (skewed read) ----
#define HSTORE(MB) do {                                                           \
    const int par_ = (MB) & 1;                                                    \
    if (sact) {                                                                   \
        _Pragma("unroll")                                                         \
        for (int r = 0; r < 6; ++r) {                                             \
            const int dd = r * 6 + sl_d;                                          \
            if (dd < DQ)                                                          \
                out[((size_t)(MB) * DQ + dd) * (B_N * H_N) + b * H_N + sl_j]      \
                    = hsh[par_][dd][(4 * sl_j) ^ dd];                             \
        }                                                                         \
    }                                                                             \
} while (0)

__global__ __launch_bounds__(128, 2)
void lstm_pc(const float* __restrict__ x, const float* __restrict__ h0,
             const float* __restrict__ c0, const float* __restrict__ Wih,
             const float* __restrict__ Whh, float* __restrict__ out)
{
    __shared__ float buf[3][DQ][LPAD];   // 24576 B pre-activations (triple-buf)
    __shared__ float hsh[2][DQ][64];     // 16384 B h ring -> total 40960 B
                                         // == 160KiB/4: four blocks/CU fit

    const int tid  = threadIdx.x;
    const int wave = tid >> 6;           // 0 = consumer, 1 = producer
    const int lane = tid & 63;
    const int b    = blockIdx.x;
    const float LOG2E = 1.4426950408889634f;

    // ---- producer state ----
    const int trow  = lane & 31;         // timestep within block (A row)
    const int koff  = (lane >> 5) * 8;   // k slice
    const int ncol  = lane & 31;         // gate column (D col)
    const int rbase = 4 * (lane >> 5);   // D row offset
    const int sl_j  = lane % H_N;        // h-store mapping
    const int sl_d  = lane / H_N;
    const bool sact = lane < 60;
    f16x8 bf0, bf1;
    f32x16 z16;
    float xr[8];

    // ---- consumer state ----
    const int p = lane & 3;
    int j = lane >> 2; if (j > H_N - 1) j = H_N - 1;
    const int crow = p * H_N + j;
    const bool writer = (wave == 0) && (p == 0) && (lane < 4 * H_N);
    half2_t wf0, wf1, wf2, wf3, wf4;     // prescaled Whh row, f16 pairs
    float cs, h;
    unsigned hp0, hp1, hp2, hp3, hp4;    // packed f16 h pairs (uniform)
    float xqA[DQ], xqB[DQ];

    if (wave == 1) {
        __builtin_amdgcn_s_setprio(0);
        // B fragments (constant): B[k][n] = sg(n)*Wih[n][k]; k>=15 or n>=40 -> 0
#pragma unroll
        for (int e = 0; e < 8; ++e) {
            const int k = koff + e;
            {
                const int n = ncol;
                const float sgn = (n >= 20 && n < 30) ? 2.0f * LOG2E : -LOG2E;
                bf0[e] = (_Float16)((k < I_N) ? sgn * Wih[n * I_N + k] : 0.0f);
            }
            {
                const int n = 32 + ncol;
                const float sgn = (n >= 20 && n < 30) ? 2.0f * LOG2E : -LOG2E;
                bf1[e] = (_Float16)((k < I_N && n < 40) ? sgn * Wih[n * I_N + k] : 0.0f);
            }
        }
#pragma unroll
        for (int r = 0; r < 16; ++r) z16[r] = 0.0f;
        // prologue: proj(0)->slot0, proj(1)->slot1; stage x(block 2)
        PLOADX(0);
        PPROJ(0);
        PLOADX(1);
        PPROJ(1);
        PLOADX(2);
    } else {
        __builtin_amdgcn_s_setprio(1);
        // prescaled Whh row for gate row crow, packed f16 pairs
        const float sg = (p == 2) ? 2.0f * LOG2E : -LOG2E;
        const float* wr = Whh + crow * H_N;
        half2_t w;
        w[0] = (_Float16)(sg * wr[0]); w[1] = (_Float16)(sg * wr[1]); wf0 = w;
        w[0] = (_Float16)(sg * wr[2]); w[1] = (_Float16)(sg * wr[3]); wf1 = w;
        w[0] = (_Float16)(sg * wr[4]); w[1] = (_Float16)(sg * wr[5]); wf2 = w;
        w[0] = (_Float16)(sg * wr[6]); w[1] = (_Float16)(sg * wr[7]); wf3 = w;
        w[0] = (_Float16)(sg * wr[8]); w[1] = (_Float16)(sg * wr[9]); wf4 = w;
        cs = c0[b * H_N + j] * (2.0f * LOG2E);
        h  = h0[b * H_N + j];
        const float hbv = dppf<0x104>(h);
        const unsigned pkh = __builtin_bit_cast(unsigned,
                                 __builtin_amdgcn_cvt_pkrtz(h, hbv));
        hp0 = rlu(pkh, 0); hp1 = rlu(pkh, 8); hp2 = rlu(pkh, 16);
        hp3 = rlu(pkh, 24); hp4 = rlu(pkh, 32);
    }
    BAR();   // slot0/slot1 projections visible

    // consumer: one-time burst read of block 0 (the only block-top stall)
    if (wave == 0) {
#pragma unroll
        for (int d = 0; d < DQ; ++d) xqA[d] = buf[0][d][crow];
    }

    // Slot rotation invariant at iter i: consumer consumes regs (block i),
    // prefetches block i+1 from slot slR; producer projects block i+2 into slW.
    int slR = 1, slW = 2, slO = 0;
    for (int m = 0; m < NBLK; m += 2) {
        if (wave == 1) {
            PPROJ(slW);
            PLOADX(m + 3);
            if (m > 0) HSTORE(m - 1);
        } else {
            CBLOCK(xqA, xqB, slR, 0);
        }
        BAR();
        { const int t = slO; slO = slR; slR = slW; slW = t; }
        if (wave == 1) {
            PPROJ(slW);
            PLOADX(m + 4);
            HSTORE(m);
        } else {
            CBLOCK(xqB, xqA, slR, 1);
        }
        BAR();
        { const int t = slO; slO = slR; slR = slW; slW = t; }
    }

    // epilogue: last h block from producer; hN/cN from consumer
    if (wave == 1) {
        HSTORE(NBLK - 1);
    } else if (writer) {
        const size_t base = (size_t)T_N * B_N * H_N;
        out[base + b * H_N + j] = h;                                          // hN
        out[base + (size_t)B_N * H_N + b * H_N + j] = cs * 0.34657359027997264f; // cN
    }
}

extern "C" void kernel_launch(void* const* d_in, const int* in_sizes, int n_in,
                              void* d_out, int out_size, void* d_ws, size_t ws_size,
                              hipStream_t stream) {
    const float* x   = (const float*)d_in[0];
    const float* h0  = (const float*)d_in[1];
    const float* c0  = (const float*)d_in[2];
    const float* Wih = (const float*)d_in[3];
    const float* Whh = (const float*)d_in[4];
    float* out = (float*)d_out;
    lstm_pc<<<dim3(B_N), dim3(128), 0, stream>>>(x, h0, c0, Wih, Whh, out);
}